// Round 1
// baseline (66.725 us; speedup 1.0000x reference)
//
#include <hip/hip_runtime.h>

// Problem shape (fixed by setup_inputs): B=8, P=256 bins, M=1*240*320=76800 pixels.
#define NB     8
#define NP     256
#define MPB    76800
#define SLICES 128
#define PER    (MPB / SLICES)   // 600 targets per block, divisible by 4

#define MIN_DEPTH 0.001f

// One block = (slice s, batch b). Thread tid owns bin-center tid.
// Stage slice targets in LDS (mask applied once), scan with 4 accumulators,
// then atomicMin (uint bit-pattern; distances >= 0 so ordering matches float).
__global__ __launch_bounds__(256) void chamfer_min_kernel(
    const float* __restrict__ bins,
    const float* __restrict__ targets,
    unsigned int* __restrict__ minbits) {
    const int b   = blockIdx.y;
    const int s   = blockIdx.x;
    const int tid = threadIdx.x;

    __shared__ float sh[PER];

    const float4* src = reinterpret_cast<const float4*>(targets + (size_t)b * MPB + (size_t)s * PER);
    for (int i = tid; i < PER / 4; i += 256) {
        float4 t = src[i];
        t.x = (t.x >= MIN_DEPTH) ? t.x : 0.0f;
        t.y = (t.y >= MIN_DEPTH) ? t.y : 0.0f;
        t.z = (t.z >= MIN_DEPTH) ? t.z : 0.0f;
        t.w = (t.w >= MIN_DEPTH) ? t.w : 0.0f;
        reinterpret_cast<float4*>(sh)[i] = t;
    }
    __syncthreads();

    const float c = 0.5f * (bins[b * (NP + 1) + tid] + bins[b * (NP + 1) + tid + 1]);

    float m0 = 1e30f, m1 = 1e30f, m2 = 1e30f, m3 = 1e30f;
    for (int i = 0; i < PER / 4; ++i) {
        float4 t = reinterpret_cast<const float4*>(sh)[i];
        m0 = fminf(m0, fabsf(c - t.x));
        m1 = fminf(m1, fabsf(c - t.y));
        m2 = fminf(m2, fabsf(c - t.z));
        m3 = fminf(m3, fabsf(c - t.w));
    }
    float m = fminf(fminf(m0, m1), fminf(m2, m3));
    atomicMin(&minbits[b * NP + tid], __float_as_uint(m));
}

// Sum the B*P minima into one scalar.
__global__ __launch_bounds__(256) void chamfer_sum_kernel(
    const unsigned int* __restrict__ minbits,
    float* __restrict__ out) {
    const int tid = threadIdx.x;
    float s = 0.0f;
    for (int i = tid; i < NB * NP; i += 256)
        s += __uint_as_float(minbits[i]);
    // wave64 reduce
    for (int off = 32; off > 0; off >>= 1)
        s += __shfl_down(s, off, 64);
    __shared__ float ws[4];
    if ((tid & 63) == 0) ws[tid >> 6] = s;
    __syncthreads();
    if (tid == 0) out[0] = ws[0] + ws[1] + ws[2] + ws[3];
}

extern "C" void kernel_launch(void* const* d_in, const int* in_sizes, int n_in,
                              void* d_out, int out_size, void* d_ws, size_t ws_size,
                              hipStream_t stream) {
    const float* bins    = (const float*)d_in[0];
    const float* targets = (const float*)d_in[1];
    float* out           = (float*)d_out;
    unsigned int* minbits = (unsigned int*)d_ws;

    // ws is re-poisoned to 0xAA before every timed launch — init to uint-max here.
    hipMemsetAsync(minbits, 0xFF, (size_t)NB * NP * sizeof(unsigned int), stream);

    dim3 grid(SLICES, NB);
    chamfer_min_kernel<<<grid, 256, 0, stream>>>(bins, targets, minbits);
    chamfer_sum_kernel<<<1, 256, 0, stream>>>(minbits, out);
}